// Round 9
// baseline (341.608 us; speedup 1.0000x reference)
//
#include <hip/hip_runtime.h>

#define NN 20000
#define EE 660000      // 640000 + 20000 self loops
#define GG 64
#define FIN 114
#define H1 3
#define F1 342         // H1*FIN
#define D2 128
#define NEG 0.2f

__device__ inline unsigned fenc(float f) {
    unsigned u = __float_as_uint(f);
    return (u & 0x80000000u) ? ~u : (u | 0x80000000u);
}
__device__ inline float fdec(unsigned u) {
    return (u & 0x80000000u) ? __uint_as_float(u & 0x7FFFFFFFu) : __uint_as_float(~u);
}
__device__ inline float lrelu(float x) { return x > 0.f ? x : NEG * x; }

// ===== fold a_src/a_dst through W1 =====
__global__ void k_wa(const float* __restrict__ W1, const float* __restrict__ aS,
                     const float* __restrict__ aD, float* __restrict__ was,
                     float* __restrict__ wad) {
    int tid = blockIdx.x * 256 + threadIdx.x;
    if (tid >= 2 * FIN * H1) return;
    int which = tid >= FIN * H1;
    int i = which ? tid - FIN * H1 : tid;
    int k = i / H1, h = i % H1;
    const float* a = which ? aD : aS;
    float s = 0.f;
    for (int d = 0; d < FIN; d++) s += W1[k * F1 + h * FIN + d] * a[h * FIN + d];
    (which ? wad : was)[i] = s;
}

// ===== W1 prep: W1P[h][k][c], k,c padded to 128 with zeros =====
__global__ void k_prep1(const float* __restrict__ W1, float* __restrict__ W1P) {
    int tid = blockIdx.x * 256 + threadIdx.x;
    if (tid >= H1 * 128 * 128) return;
    int h = tid / (128 * 128);
    int rem = tid & (128 * 128 - 1);
    int k = rem >> 7, c = rem & 127;
    W1P[tid] = (c < FIN && k < FIN) ? W1[k * F1 + h * FIN + c] : 0.f;
}

// ===== W2 prep: W2P[h*128+k][c] = W2[(h*114+k)*128+c], k<114 else 0 (K padded 384) =====
__global__ void k_prep2(const float* __restrict__ W2, float* __restrict__ W2P) {
    int tid = blockIdx.x * 256 + threadIdx.x;
    if (tid >= 3 * 128 * 128) return;
    int hk = tid >> 7, c = tid & 127;
    int h = hk >> 7, k = hk & 127;
    W2P[tid] = (k < FIN) ? W2[(h * FIN + k) * D2 + c] : 0.f;
}

// ===== as1/ad1 = x @ was/wad =====
__global__ __launch_bounds__(256) void k_alpha1x(const float* __restrict__ x,
                                                 const float* __restrict__ was,
                                                 const float* __restrict__ wad,
                                                 float* __restrict__ as1,
                                                 float* __restrict__ ad1) {
    int n = blockIdx.x * 4 + (threadIdx.x >> 6);
    int l = threadIdx.x & 63;
    if (n >= NN) return;
    float x0 = x[n * FIN + l];
    float x1 = (l < FIN - 64) ? x[n * FIN + 64 + l] : 0.f;
    float s[H1], d[H1];
#pragma unroll
    for (int h = 0; h < H1; h++) {
        float w0s = was[l * H1 + h], w0d = wad[l * H1 + h];
        float w1s = (l < FIN - 64) ? was[(64 + l) * H1 + h] : 0.f;
        float w1d = (l < FIN - 64) ? wad[(64 + l) * H1 + h] : 0.f;
        s[h] = x0 * w0s + x1 * w1s;
        d[h] = x0 * w0d + x1 * w1d;
    }
#pragma unroll
    for (int o = 32; o > 0; o >>= 1) {
#pragma unroll
        for (int h = 0; h < H1; h++) {
            s[h] += __shfl_down(s[h], o);
            d[h] += __shfl_down(d[h], o);
        }
    }
    if (l == 0) {
#pragma unroll
        for (int h = 0; h < H1; h++) {
            as1[n * H1 + h] = s[h];
            ad1[n * H1 + h] = d[h];
        }
    }
}

// ===================== CSR build =====================
__global__ void k_count(const int* __restrict__ dst, int* __restrict__ cnt) {
    int e = blockIdx.x * 256 + threadIdx.x;
    if (e < EE) atomicAdd(&cnt[dst[e]], 1);
}

__global__ __launch_bounds__(1024) void k_scan(const int* __restrict__ cnt,
                                               int* __restrict__ off) {
    __shared__ int part[1024];
    int t = threadIdx.x;
    const int CH = 20;
    int loc[CH];
    int s = 0;
    int base = t * CH;
    for (int i = 0; i < CH; i++) {
        int idx = base + i;
        int v = (idx < NN) ? cnt[idx] : 0;
        loc[i] = s;
        s += v;
    }
    part[t] = s;
    __syncthreads();
    for (int d = 1; d < 1024; d <<= 1) {
        int v = (t >= d) ? part[t - d] : 0;
        __syncthreads();
        part[t] += v;
        __syncthreads();
    }
    int pre = (t == 0) ? 0 : part[t - 1];
    for (int i = 0; i < CH; i++) {
        int idx = base + i;
        if (idx < NN) off[idx] = pre + loc[i];
    }
    if (t == 1023) off[NN] = part[1023];
}

__global__ void k_scatter(const int* __restrict__ src, const int* __restrict__ dst,
                          const int* __restrict__ off, int* __restrict__ cur,
                          int* __restrict__ csr_src) {
    int e = blockIdx.x * 256 + threadIdx.x;
    if (e < EE) {
        int d = dst[e];
        int pos = off[d] + atomicAdd(&cur[d], 1);
        csr_src[pos] = src[e];
    }
}

// ===== layer-1: fused softmax+aggregate of x into xaggP[3][N][128] (zero-padded) =====
__global__ __launch_bounds__(128) void k_aggx(const float* __restrict__ x,
                                              const float* __restrict__ as1,
                                              const float* __restrict__ ad1,
                                              const int* __restrict__ off,
                                              const int* __restrict__ csr_src,
                                              float* __restrict__ xaggP) {
    int n = blockIdx.x, t = threadIdx.x;
    int e0 = off[n], e1 = off[n + 1];
    float adv0 = ad1[n * H1 + 0], adv1 = ad1[n * H1 + 1], adv2 = ad1[n * H1 + 2];
    __shared__ int ssrc[64];
    __shared__ float sw[64][H1];
    __shared__ float red[64][H1];
    float acc0 = 0.f, acc1 = 0.f, acc2 = 0.f;
    float ps0 = 0.f, ps1 = 0.f, ps2 = 0.f;
    for (int base = e0; base < e1; base += 64) {
        int c = min(64, e1 - base);
        __syncthreads();
        if (t < c) {
            int s = csr_src[base + t];
            ssrc[t] = s;
            float w0 = __expf(lrelu(as1[s * H1 + 0] + adv0));
            float w1 = __expf(lrelu(as1[s * H1 + 1] + adv1));
            float w2 = __expf(lrelu(as1[s * H1 + 2] + adv2));
            sw[t][0] = w0; sw[t][1] = w1; sw[t][2] = w2;
            ps0 += w0; ps1 += w1; ps2 += w2;
        }
        __syncthreads();
        if (t < FIN) {
            for (int j = 0; j < c; j++) {
                float xv = x[ssrc[j] * FIN + t];
                acc0 += xv * sw[j][0];
                acc1 += xv * sw[j][1];
                acc2 += xv * sw[j][2];
            }
        }
    }
    __syncthreads();
    if (t < 64) { red[t][0] = ps0; red[t][1] = ps1; red[t][2] = ps2; }
    __syncthreads();
    for (int sr = 32; sr > 0; sr >>= 1) {
        if (t < sr) {
            red[t][0] += red[t + sr][0];
            red[t][1] += red[t + sr][1];
            red[t][2] += red[t + sr][2];
        }
        __syncthreads();
    }
    float i0 = 1.f / red[0][0], i1 = 1.f / red[0][1], i2 = 1.f / red[0][2];
    float v0 = (t < FIN) ? acc0 * i0 : 0.f;
    float v1 = (t < FIN) ? acc1 * i1 : 0.f;
    float v2 = (t < FIN) ? acc2 * i2 : 0.f;
    xaggP[(size_t)0 * NN * 128 + n * 128 + t] = v0;
    xaggP[(size_t)1 * NN * 128 + n * 128 + t] = v1;
    xaggP[(size_t)2 * NN * 128 + n * 128 + t] = v2;
}

// ===== GEMM1: h1aP[h] = ELU(xaggP_h @ W1P_h + b1). 128 thr, BM=64 BN=128 BK=16,
// micro-tile 8x8 (rows tr*8.., cols {tc*4, 64+tc*4}); As transposed [k][64+pad].
__global__ __launch_bounds__(128) void k_gemm1n(const float* __restrict__ xaggP,
                                                const float* __restrict__ W1P,
                                                const float* __restrict__ b1,
                                                float* __restrict__ h1aP) {
    int h = blockIdx.y;
    int rb = blockIdx.x * 64;
    int t = threadIdx.x;
    int tr = t >> 4, tc = t & 15;
    __shared__ float As[16][68];
    __shared__ float Bs[16][132];
    const float* Ap = xaggP + (size_t)h * NN * 128;
    const float* Bp = W1P + (size_t)h * 128 * 128;
    const float4 zf4 = make_float4(0.f, 0.f, 0.f, 0.f);
    // staging maps
    int ar = t >> 1, aks = (t & 1) * 8;          // A: row ar, k aks..aks+7 (2 f4)
    int bkr = t >> 3, bnc = (t & 7) * 16;        // B: k-row bkr, cols bnc..bnc+15 (4 f4)
    float4 aR[2], bR[4];
    {
        int g = rb + ar;
        aR[0] = (g < NN) ? *(const float4*)(Ap + (size_t)g * 128 + aks) : zf4;
        aR[1] = (g < NN) ? *(const float4*)(Ap + (size_t)g * 128 + aks + 4) : zf4;
#pragma unroll
        for (int q = 0; q < 4; q++)
            bR[q] = *(const float4*)(Bp + (size_t)bkr * 128 + bnc + q * 4);
    }
    float acc[8][8] = {};
    for (int tile = 0; tile < 8; tile++) {
        if (tile) __syncthreads();
#pragma unroll
        for (int j = 0; j < 4; j++) {
            As[aks + j][ar] = ((const float*)&aR[0])[j];
            As[aks + 4 + j][ar] = ((const float*)&aR[1])[j];
        }
#pragma unroll
        for (int q = 0; q < 4; q++) *(float4*)(&Bs[bkr][bnc + q * 4]) = bR[q];
        __syncthreads();
        if (tile < 7) {
            int k0 = (tile + 1) * 16;
            int g = rb + ar;
            aR[0] = (g < NN) ? *(const float4*)(Ap + (size_t)g * 128 + k0 + aks) : zf4;
            aR[1] = (g < NN) ? *(const float4*)(Ap + (size_t)g * 128 + k0 + aks + 4) : zf4;
#pragma unroll
            for (int q = 0; q < 4; q++)
                bR[q] = *(const float4*)(Bp + (size_t)(k0 + bkr) * 128 + bnc + q * 4);
        }
#pragma unroll
        for (int k = 0; k < 16; k++) {
            float a8[8], b8[8];
            *(float4*)(a8 + 0) = *(const float4*)(&As[k][tr * 8]);
            *(float4*)(a8 + 4) = *(const float4*)(&As[k][tr * 8 + 4]);
            *(float4*)(b8 + 0) = *(const float4*)(&Bs[k][tc * 4]);
            *(float4*)(b8 + 4) = *(const float4*)(&Bs[k][64 + tc * 4]);
#pragma unroll
            for (int r = 0; r < 8; r++)
#pragma unroll
                for (int j = 0; j < 8; j++) acc[r][j] += a8[r] * b8[j];
        }
    }
    // epilogue: bias+ELU; pad cols (>=114) -> 0; 2 f4 stores per row
    float* Hp = h1aP + (size_t)h * NN * 128;
    int c0 = tc * 4, c1 = 64 + tc * 4;
    float bv[8];
#pragma unroll
    for (int j = 0; j < 4; j++) {
        bv[j] = b1[h * FIN + c0 + j];
        bv[4 + j] = (c1 + j < FIN) ? b1[h * FIN + c1 + j] : 0.f;
    }
#pragma unroll
    for (int r = 0; r < 8; r++) {
        int row = rb + tr * 8 + r;
        if (row >= NN) continue;
        float v[8];
#pragma unroll
        for (int j = 0; j < 8; j++) {
            float w = acc[r][j] + bv[j];
            w = w > 0.f ? w : expm1f(w);
            v[j] = ((j < 4) || (c1 + j - 4 < FIN)) ? w : 0.f;
        }
        *(float4*)(Hp + (size_t)row * 128 + c0) = make_float4(v[0], v[1], v[2], v[3]);
        *(float4*)(Hp + (size_t)row * 128 + c1) = make_float4(v[4], v[5], v[6], v[7]);
    }
}

// ===== GEMM2: h2h[ks] = h1aP @ W2P over K-half ks (192 each). Same structure. =====
__global__ __launch_bounds__(128) void k_gemm2n(const float* __restrict__ h1aP,
                                                const float* __restrict__ W2P,
                                                float* __restrict__ h2h) {
    int ks = blockIdx.y;
    int rb = blockIdx.x * 64;
    int kbase = ks * 192;
    int t = threadIdx.x;
    int tr = t >> 4, tc = t & 15;
    __shared__ float As[16][68];
    __shared__ float Bs[16][132];
    const float4 zf4 = make_float4(0.f, 0.f, 0.f, 0.f);
    int ar = t >> 1, aks = (t & 1) * 8;
    int bkr = t >> 3, bnc = (t & 7) * 16;
    auto loadA = [&](int row, int kg) -> float4 {
        if (row >= NN) return zf4;
        int hh = kg >> 7, kc = kg & 127;
        return *(const float4*)(h1aP + ((size_t)hh * NN + row) * 128 + kc);
    };
    float4 aR[2], bR[4];
    {
        int g = rb + ar;
        aR[0] = loadA(g, kbase + aks);
        aR[1] = loadA(g, kbase + aks + 4);
#pragma unroll
        for (int q = 0; q < 4; q++)
            bR[q] = *(const float4*)(W2P + (size_t)(kbase + bkr) * 128 + bnc + q * 4);
    }
    float acc[8][8] = {};
    for (int tile = 0; tile < 12; tile++) {
        if (tile) __syncthreads();
#pragma unroll
        for (int j = 0; j < 4; j++) {
            As[aks + j][ar] = ((const float*)&aR[0])[j];
            As[aks + 4 + j][ar] = ((const float*)&aR[1])[j];
        }
#pragma unroll
        for (int q = 0; q < 4; q++) *(float4*)(&Bs[bkr][bnc + q * 4]) = bR[q];
        __syncthreads();
        if (tile < 11) {
            int k0 = kbase + (tile + 1) * 16;
            int g = rb + ar;
            aR[0] = loadA(g, k0 + aks);
            aR[1] = loadA(g, k0 + aks + 4);
#pragma unroll
            for (int q = 0; q < 4; q++)
                bR[q] = *(const float4*)(W2P + (size_t)(k0 + bkr) * 128 + bnc + q * 4);
        }
#pragma unroll
        for (int k = 0; k < 16; k++) {
            float a8[8], b8[8];
            *(float4*)(a8 + 0) = *(const float4*)(&As[k][tr * 8]);
            *(float4*)(a8 + 4) = *(const float4*)(&As[k][tr * 8 + 4]);
            *(float4*)(b8 + 0) = *(const float4*)(&Bs[k][tc * 4]);
            *(float4*)(b8 + 4) = *(const float4*)(&Bs[k][64 + tc * 4]);
#pragma unroll
            for (int r = 0; r < 8; r++)
#pragma unroll
                for (int j = 0; j < 8; j++) acc[r][j] += a8[r] * b8[j];
        }
    }
    float* Hp = h2h + (size_t)ks * NN * 128;
    int c0 = tc * 4, c1 = 64 + tc * 4;
#pragma unroll
    for (int r = 0; r < 8; r++) {
        int row = rb + tr * 8 + r;
        if (row >= NN) continue;
        *(float4*)(Hp + (size_t)row * 128 + c0) =
            make_float4(acc[r][0], acc[r][1], acc[r][2], acc[r][3]);
        *(float4*)(Hp + (size_t)row * 128 + c1) =
            make_float4(acc[r][4], acc[r][5], acc[r][6], acc[r][7]);
    }
}

// ===== alpha2 + K-half fold: h2 = h2a+h2b; as2/ad2 = h2 . aS2/aD2 =====
__global__ __launch_bounds__(256) void k_alpha2(const float* __restrict__ h2h,
                                                const float* __restrict__ aS,
                                                const float* __restrict__ aD,
                                                float* __restrict__ h2,
                                                float* __restrict__ as2,
                                                float* __restrict__ ad2) {
    int n = blockIdx.x * 4 + (threadIdx.x >> 6);
    int l = threadIdx.x & 63;
    if (n >= NN) return;
    const float* pa = h2h + (size_t)n * D2;
    const float* pb = h2h + (size_t)NN * D2 + (size_t)n * D2;
    float v0 = pa[l] + pb[l];
    float v1 = pa[64 + l] + pb[64 + l];
    h2[(size_t)n * D2 + l] = v0;
    h2[(size_t)n * D2 + 64 + l] = v1;
    float ps = v0 * aS[l] + v1 * aS[64 + l];
    float pd = v0 * aD[l] + v1 * aD[64 + l];
    for (int o = 32; o > 0; o >>= 1) {
        ps += __shfl_down(ps, o);
        pd += __shfl_down(pd, o);
    }
    if (l == 0) {
        as2[n] = ps;
        ad2[n] = pd;
    }
}

// ===== layer-2: fused softmax+aggregate+relu+POOL (atomicMax into poolbuf) =====
__global__ __launch_bounds__(128) void k_agg2f(const float* __restrict__ h2,
                                               const float* __restrict__ as2,
                                               const float* __restrict__ ad2,
                                               const int* __restrict__ off,
                                               const int* __restrict__ csr_src,
                                               const float* __restrict__ b2,
                                               unsigned* __restrict__ poolbuf) {
    int n = blockIdx.x, t = threadIdx.x;
    int e0 = off[n], e1 = off[n + 1];
    float adv = ad2[n];
    __shared__ int ssrc[64];
    __shared__ float sw[64];
    __shared__ float red[64];
    float acc = 0.f, ps = 0.f;
    for (int base = e0; base < e1; base += 64) {
        int c = min(64, e1 - base);
        __syncthreads();
        if (t < c) {
            int s = csr_src[base + t];
            ssrc[t] = s;
            float w = __expf(lrelu(as2[s] + adv));
            sw[t] = w;
            ps += w;
        }
        __syncthreads();
        for (int j = 0; j < c; j++) acc += h2[(size_t)ssrc[j] * D2 + t] * sw[j];
    }
    __syncthreads();
    if (t < 64) red[t] = ps;
    __syncthreads();
    for (int sr = 32; sr > 0; sr >>= 1) {
        if (t < sr) red[t] += red[t + sr];
        __syncthreads();
    }
    float v = fmaxf(acc / red[0] + b2[t], 0.f);
    int g = (int)(((long long)n * GG) / NN);   // batch[n] = n*G//N
    atomicMax(&poolbuf[g * D2 + t], fenc(v));
}

// ===== MLP head =====
__global__ __launch_bounds__(128) void k_mlp(const unsigned* __restrict__ poolbuf,
                                             const float* __restrict__ Wg,
                                             const float* __restrict__ bg,
                                             const float* __restrict__ Wf1,
                                             const float* __restrict__ bf1,
                                             const float* __restrict__ Wf2,
                                             const float* __restrict__ bf2,
                                             const float* __restrict__ Wo,
                                             const float* __restrict__ bo,
                                             float* __restrict__ out) {
    int g = blockIdx.x;
    int t = threadIdx.x;
    __shared__ float pool[D2];
    __shared__ float a1[64];
    __shared__ float a2[32];
    __shared__ float a3[16];
    pool[t] = fdec(poolbuf[g * D2 + t]);
    __syncthreads();
    if (t < 64) {
        float acc = bg[t];
        for (int k = 0; k < D2; k++) acc += pool[k] * Wg[k * 64 + t];
        a1[t] = fmaxf(acc, 0.f);
    }
    __syncthreads();
    if (t < 32) {
        float acc = bf1[t];
        for (int k = 0; k < 64; k++) acc += a1[k] * Wf1[k * 32 + t];
        a2[t] = fmaxf(acc, 0.f);
    }
    __syncthreads();
    if (t < 16) {
        float acc = bf2[t];
        for (int k = 0; k < 32; k++) acc += a2[k] * Wf2[k * 16 + t];
        a3[t] = fmaxf(acc, 0.f);
    }
    __syncthreads();
    if (t == 0) {
        float acc = bo[0];
        for (int k = 0; k < 16; k++) acc += a3[k] * Wo[k];
        out[g] = acc;
    }
}

extern "C" void kernel_launch(void* const* d_in, const int* in_sizes, int n_in,
                              void* d_out, int out_size, void* d_ws, size_t ws_size,
                              hipStream_t stream) {
    const float* x = (const float*)d_in[0];
    const int* ei = (const int*)d_in[1];
    const float* W1 = (const float*)d_in[3];
    const float* aS1 = (const float*)d_in[4];
    const float* aD1 = (const float*)d_in[5];
    const float* b1 = (const float*)d_in[6];
    const float* W2 = (const float*)d_in[7];
    const float* aS2 = (const float*)d_in[8];
    const float* aD2 = (const float*)d_in[9];
    const float* b2 = (const float*)d_in[10];
    const float* Wg = (const float*)d_in[11];
    const float* bg = (const float*)d_in[12];
    const float* Wf1 = (const float*)d_in[13];
    const float* bf1 = (const float*)d_in[14];
    const float* Wf2 = (const float*)d_in[15];
    const float* bf2 = (const float*)d_in[16];
    const float* Wo = (const float*)d_in[17];
    const float* bo = (const float*)d_in[18];
    float* out = (float*)d_out;

    const int* src = ei;
    const int* dst = ei + EE;

    char* ws = (char*)d_ws;
    size_t o = 0;
    auto alloc = [&](size_t bytes) -> char* {
        char* p = ws + o;
        o += (bytes + 255) & ~(size_t)255;
        return p;
    };
    float* was = (float*)alloc((size_t)FIN * H1 * 4);
    float* wad = (float*)alloc((size_t)FIN * H1 * 4);
    float* W1P = (float*)alloc((size_t)H1 * 128 * 128 * 4);
    float* W2P = (float*)alloc((size_t)3 * 128 * 128 * 4);
    float* as1 = (float*)alloc((size_t)NN * H1 * 4);
    float* ad1 = (float*)alloc((size_t)NN * H1 * 4);
    int* cnt = (int*)alloc((size_t)NN * 4);
    int* off = (int*)alloc((size_t)(NN + 1) * 4);
    int* cur = (int*)alloc((size_t)NN * 4);
    int* csr_src = (int*)alloc((size_t)EE * 4);
    float* xaggP = (float*)alloc((size_t)H1 * NN * 128 * 4);
    float* h1aP = (float*)alloc((size_t)H1 * NN * 128 * 4);
    float* h2h = (float*)alloc((size_t)2 * NN * D2 * 4);
    float* h2 = (float*)alloc((size_t)NN * D2 * 4);
    float* as2 = (float*)alloc((size_t)NN * 4);
    float* ad2 = (float*)alloc((size_t)NN * 4);
    unsigned* poolbuf = (unsigned*)alloc((size_t)GG * D2 * 4);
    (void)ws_size;

    hipMemsetAsync(cnt, 0, (size_t)NN * 4, stream);
    hipMemsetAsync(cur, 0, (size_t)NN * 4, stream);
    hipMemsetAsync(poolbuf, 0, (size_t)GG * D2 * 4, stream);

    const int EB = (EE + 255) / 256;

    k_wa<<<(2 * FIN * H1 + 255) / 256, 256, 0, stream>>>(W1, aS1, aD1, was, wad);
    k_prep1<<<(H1 * 128 * 128 + 255) / 256, 256, 0, stream>>>(W1, W1P);
    k_prep2<<<(3 * 128 * 128 + 255) / 256, 256, 0, stream>>>(W2, W2P);
    k_alpha1x<<<(NN + 3) / 4, 256, 0, stream>>>(x, was, wad, as1, ad1);
    k_count<<<EB, 256, 0, stream>>>(dst, cnt);
    k_scan<<<1, 1024, 0, stream>>>(cnt, off);
    k_scatter<<<EB, 256, 0, stream>>>(src, dst, off, cur, csr_src);
    k_aggx<<<NN, 128, 0, stream>>>(x, as1, ad1, off, csr_src, xaggP);
    k_gemm1n<<<dim3((NN + 63) / 64, H1), 128, 0, stream>>>(xaggP, W1P, b1, h1aP);
    k_gemm2n<<<dim3((NN + 63) / 64, 2), 128, 0, stream>>>(h1aP, W2P, h2h);
    k_alpha2<<<(NN + 3) / 4, 256, 0, stream>>>(h2h, aS2, aD2, h2, as2, ad2);
    k_agg2f<<<NN, 128, 0, stream>>>(h2, as2, ad2, off, csr_src, b2, poolbuf);
    k_mlp<<<GG, 128, 0, stream>>>(poolbuf, Wg, bg, Wf1, bf1, Wf2, bf2, Wo, bo, out);
}

// Round 10
// 328.609 us; speedup vs baseline: 1.0396x; 1.0396x over previous
//
#include <hip/hip_runtime.h>

#define NN 20000
#define EE 660000      // 640000 + 20000 self loops
#define GG 64
#define FIN 114
#define H1 3
#define F1 342         // H1*FIN
#define D2 128
#define NEG 0.2f

typedef __attribute__((ext_vector_type(8))) short short8v;
typedef __attribute__((ext_vector_type(4))) float f32x4;
typedef unsigned short ushort_t;

__device__ inline unsigned fenc(float f) {
    unsigned u = __float_as_uint(f);
    return (u & 0x80000000u) ? ~u : (u | 0x80000000u);
}
__device__ inline float fdec(unsigned u) {
    return (u & 0x80000000u) ? __uint_as_float(u & 0x7FFFFFFFu) : __uint_as_float(~u);
}
__device__ inline float lrelu(float x) { return x > 0.f ? x : NEG * x; }

// fp32 -> bf16 hi (truncate) + bf16 lo (RNE of residual); x ≈ hi + lo to ~2^-17
__device__ inline void split2(float x, ushort_t& hi, ushort_t& lo) {
    unsigned u = __float_as_uint(x);
    unsigned uh = u & 0xFFFF0000u;
    hi = (ushort_t)(uh >> 16);
    float r = x - __uint_as_float(uh);
    unsigned v = __float_as_uint(r);
    unsigned vh = (v + 0x7FFFu + ((v >> 16) & 1u)) & 0xFFFF0000u;
    lo = (ushort_t)(vh >> 16);
}

// ===== fold a_src/a_dst through W1 =====
__global__ void k_wa(const float* __restrict__ W1, const float* __restrict__ aS,
                     const float* __restrict__ aD, float* __restrict__ was,
                     float* __restrict__ wad) {
    int tid = blockIdx.x * 256 + threadIdx.x;
    if (tid >= 2 * FIN * H1) return;
    int which = tid >= FIN * H1;
    int i = which ? tid - FIN * H1 : tid;
    int k = i / H1, h = i % H1;
    const float* a = which ? aD : aS;
    float s = 0.f;
    for (int d = 0; d < FIN; d++) s += W1[k * F1 + h * FIN + d] * a[h * FIN + d];
    (which ? wad : was)[i] = s;
}

// ===== W1 prep: W1T[h][c][k] hi/lo bf16, c,k in [0,128) zero-padded =====
__global__ void k_prep1m(const float* __restrict__ W1, ushort_t* __restrict__ W1Th,
                         ushort_t* __restrict__ W1Tl) {
    int tid = blockIdx.x * 256 + threadIdx.x;
    if (tid >= H1 * 128 * 128) return;
    int h = tid / (128 * 128);
    int rem = tid & (128 * 128 - 1);
    int c = rem >> 7, k = rem & 127;
    float v = (c < FIN && k < FIN) ? W1[k * F1 + h * FIN + c] : 0.f;
    ushort_t hi, lo;
    split2(v, hi, lo);
    W1Th[tid] = hi;
    W1Tl[tid] = lo;
}

// ===== W2 prep: W2T[c][hk] hi/lo bf16, hk = h*128+k (k zero-padded 114..127) =====
__global__ void k_prep2m(const float* __restrict__ W2, ushort_t* __restrict__ W2Th,
                         ushort_t* __restrict__ W2Tl) {
    int tid = blockIdx.x * 256 + threadIdx.x;
    if (tid >= 128 * 384) return;
    int c = tid / 384;
    int hk = tid - c * 384;
    int h = hk >> 7, k = hk & 127;
    float v = (k < FIN) ? W2[(h * FIN + k) * D2 + c] : 0.f;
    ushort_t hi, lo;
    split2(v, hi, lo);
    W2Th[tid] = hi;
    W2Tl[tid] = lo;
}

// ===== as1/ad1 = x @ was/wad =====
__global__ __launch_bounds__(256) void k_alpha1x(const float* __restrict__ x,
                                                 const float* __restrict__ was,
                                                 const float* __restrict__ wad,
                                                 float* __restrict__ as1,
                                                 float* __restrict__ ad1) {
    int n = blockIdx.x * 4 + (threadIdx.x >> 6);
    int l = threadIdx.x & 63;
    if (n >= NN) return;
    float x0 = x[n * FIN + l];
    float x1 = (l < FIN - 64) ? x[n * FIN + 64 + l] : 0.f;
    float s[H1], d[H1];
#pragma unroll
    for (int h = 0; h < H1; h++) {
        float w0s = was[l * H1 + h], w0d = wad[l * H1 + h];
        float w1s = (l < FIN - 64) ? was[(64 + l) * H1 + h] : 0.f;
        float w1d = (l < FIN - 64) ? wad[(64 + l) * H1 + h] : 0.f;
        s[h] = x0 * w0s + x1 * w1s;
        d[h] = x0 * w0d + x1 * w1d;
    }
#pragma unroll
    for (int o = 32; o > 0; o >>= 1) {
#pragma unroll
        for (int h = 0; h < H1; h++) {
            s[h] += __shfl_down(s[h], o);
            d[h] += __shfl_down(d[h], o);
        }
    }
    if (l == 0) {
#pragma unroll
        for (int h = 0; h < H1; h++) {
            as1[n * H1 + h] = s[h];
            ad1[n * H1 + h] = d[h];
        }
    }
}

// ===================== CSR build =====================
__global__ void k_count(const int* __restrict__ dst, int* __restrict__ cnt) {
    int e = blockIdx.x * 256 + threadIdx.x;
    if (e < EE) atomicAdd(&cnt[dst[e]], 1);
}

__global__ __launch_bounds__(1024) void k_scan(const int* __restrict__ cnt,
                                               int* __restrict__ off) {
    __shared__ int part[1024];
    int t = threadIdx.x;
    const int CH = 20;
    int loc[CH];
    int s = 0;
    int base = t * CH;
    for (int i = 0; i < CH; i++) {
        int idx = base + i;
        int v = (idx < NN) ? cnt[idx] : 0;
        loc[i] = s;
        s += v;
    }
    part[t] = s;
    __syncthreads();
    for (int d = 1; d < 1024; d <<= 1) {
        int v = (t >= d) ? part[t - d] : 0;
        __syncthreads();
        part[t] += v;
        __syncthreads();
    }
    int pre = (t == 0) ? 0 : part[t - 1];
    for (int i = 0; i < CH; i++) {
        int idx = base + i;
        if (idx < NN) off[idx] = pre + loc[i];
    }
    if (t == 1023) off[NN] = part[1023];
}

__global__ void k_scatter(const int* __restrict__ src, const int* __restrict__ dst,
                          const int* __restrict__ off, int* __restrict__ cur,
                          int* __restrict__ csr_src) {
    int e = blockIdx.x * 256 + threadIdx.x;
    if (e < EE) {
        int d = dst[e];
        int pos = off[d] + atomicAdd(&cur[d], 1);
        csr_src[pos] = src[e];
    }
}

// ===== layer-1: fused softmax+aggregate of x -> xg hi/lo bf16 [3][N][128] =====
__global__ __launch_bounds__(128) void k_aggx(const float* __restrict__ x,
                                              const float* __restrict__ as1,
                                              const float* __restrict__ ad1,
                                              const int* __restrict__ off,
                                              const int* __restrict__ csr_src,
                                              ushort_t* __restrict__ xgh,
                                              ushort_t* __restrict__ xgl) {
    int n = blockIdx.x, t = threadIdx.x;
    int e0 = off[n], e1 = off[n + 1];
    float adv0 = ad1[n * H1 + 0], adv1 = ad1[n * H1 + 1], adv2 = ad1[n * H1 + 2];
    __shared__ int ssrc[64];
    __shared__ float sw[64][H1];
    __shared__ float red[64][H1];
    float acc0 = 0.f, acc1 = 0.f, acc2 = 0.f;
    float ps0 = 0.f, ps1 = 0.f, ps2 = 0.f;
    for (int base = e0; base < e1; base += 64) {
        int c = min(64, e1 - base);
        __syncthreads();
        if (t < c) {
            int s = csr_src[base + t];
            ssrc[t] = s;
            float w0 = __expf(lrelu(as1[s * H1 + 0] + adv0));
            float w1 = __expf(lrelu(as1[s * H1 + 1] + adv1));
            float w2 = __expf(lrelu(as1[s * H1 + 2] + adv2));
            sw[t][0] = w0; sw[t][1] = w1; sw[t][2] = w2;
            ps0 += w0; ps1 += w1; ps2 += w2;
        }
        __syncthreads();
        if (t < FIN) {
            for (int j = 0; j < c; j++) {
                float xv = x[ssrc[j] * FIN + t];
                acc0 += xv * sw[j][0];
                acc1 += xv * sw[j][1];
                acc2 += xv * sw[j][2];
            }
        }
    }
    __syncthreads();
    if (t < 64) { red[t][0] = ps0; red[t][1] = ps1; red[t][2] = ps2; }
    __syncthreads();
    for (int sr = 32; sr > 0; sr >>= 1) {
        if (t < sr) {
            red[t][0] += red[t + sr][0];
            red[t][1] += red[t + sr][1];
            red[t][2] += red[t + sr][2];
        }
        __syncthreads();
    }
    float i0 = 1.f / red[0][0], i1 = 1.f / red[0][1], i2 = 1.f / red[0][2];
    float v0 = (t < FIN) ? acc0 * i0 : 0.f;
    float v1 = (t < FIN) ? acc1 * i1 : 0.f;
    float v2 = (t < FIN) ? acc2 * i2 : 0.f;
    ushort_t hi, lo;
    split2(v0, hi, lo);
    xgh[(size_t)0 * NN * 128 + n * 128 + t] = hi;
    xgl[(size_t)0 * NN * 128 + n * 128 + t] = lo;
    split2(v1, hi, lo);
    xgh[(size_t)1 * NN * 128 + n * 128 + t] = hi;
    xgl[(size_t)1 * NN * 128 + n * 128 + t] = lo;
    split2(v2, hi, lo);
    xgh[(size_t)2 * NN * 128 + n * 128 + t] = hi;
    xgl[(size_t)2 * NN * 128 + n * 128 + t] = lo;
}

// ===== GEMM1 (MFMA bf16x3): h1 = ELU(xagg_h @ W1_h + b1) -> hi/lo planes =====
// grid (313,3) x 256 thr (4 waves). Wave w: rows rb+w*16..+15, all 128 cols.
// A frag: lane(m=l&15,g=l>>4) = xg[h][row][k0+g*8..+7]; B frag: W1T[h][c][k0+g*8..].
// C/D: col=l&15, row=(l>>4)*4+r  [HW-verified m89].
__global__ __launch_bounds__(256) void k_gemm1m(const ushort_t* __restrict__ xgh,
                                                const ushort_t* __restrict__ xgl,
                                                const ushort_t* __restrict__ W1Th,
                                                const ushort_t* __restrict__ W1Tl,
                                                const float* __restrict__ b1,
                                                ushort_t* __restrict__ h1hi,
                                                ushort_t* __restrict__ h1lo) {
    int h = blockIdx.y;
    int rb = blockIdx.x * 64;
    int w = threadIdx.x >> 6, l = threadIdx.x & 63;
    int m = l & 15, g = l >> 4;
    int row = rb + w * 16 + m;
    bool rok = (row < NN);
    const size_t abase = ((size_t)h * NN + (size_t)(rok ? row : 0)) * 128;
    const short8v z8 = {0, 0, 0, 0, 0, 0, 0, 0};
    f32x4 acc[8];
#pragma unroll
    for (int j = 0; j < 8; j++) acc[j] = (f32x4){0.f, 0.f, 0.f, 0.f};
    for (int k0 = 0; k0 < 128; k0 += 32) {
        short8v ah = rok ? *(const short8v*)(xgh + abase + k0 + g * 8) : z8;
        short8v al = rok ? *(const short8v*)(xgl + abase + k0 + g * 8) : z8;
#pragma unroll
        for (int j = 0; j < 8; j++) {
            int c = j * 16 + m;
            size_t bo = ((size_t)h * 128 + c) * 128 + k0 + g * 8;
            short8v bh = *(const short8v*)(W1Th + bo);
            short8v bl = *(const short8v*)(W1Tl + bo);
            acc[j] = __builtin_amdgcn_mfma_f32_16x16x32_bf16(ah, bh, acc[j], 0, 0, 0);
            acc[j] = __builtin_amdgcn_mfma_f32_16x16x32_bf16(ah, bl, acc[j], 0, 0, 0);
            acc[j] = __builtin_amdgcn_mfma_f32_16x16x32_bf16(al, bh, acc[j], 0, 0, 0);
        }
    }
    // epilogue: bias + ELU + bf16 split; pad cols -> 0
#pragma unroll
    for (int j = 0; j < 8; j++) {
        int c = j * 16 + m;
        float bv = (c < FIN) ? b1[h * FIN + c] : 0.f;
#pragma unroll
        for (int r = 0; r < 4; r++) {
            int orow = rb + w * 16 + g * 4 + r;
            if (orow >= NN) continue;
            float v = acc[j][r] + bv;
            v = v > 0.f ? v : expm1f(v);
            ushort_t hi = 0, lo = 0;
            if (c < FIN) split2(v, hi, lo);
            size_t oo = ((size_t)h * NN + orow) * 128 + c;
            h1hi[oo] = hi;
            h1lo[oo] = lo;
        }
    }
}

// ===== GEMM2 (MFMA bf16x3): h2 = h1 @ W2, K=384 (head-major, pads zero) =====
__global__ __launch_bounds__(256) void k_gemm2m(const ushort_t* __restrict__ h1hi,
                                                const ushort_t* __restrict__ h1lo,
                                                const ushort_t* __restrict__ W2Th,
                                                const ushort_t* __restrict__ W2Tl,
                                                float* __restrict__ h2) {
    int rb = blockIdx.x * 64;
    int w = threadIdx.x >> 6, l = threadIdx.x & 63;
    int m = l & 15, g = l >> 4;
    int row = rb + w * 16 + m;
    bool rok = (row < NN);
    const short8v z8 = {0, 0, 0, 0, 0, 0, 0, 0};
    f32x4 acc[8];
#pragma unroll
    for (int j = 0; j < 8; j++) acc[j] = (f32x4){0.f, 0.f, 0.f, 0.f};
    for (int k0 = 0; k0 < 384; k0 += 32) {
        int hh = k0 >> 7, kc = (k0 & 127) + g * 8;
        size_t ao = ((size_t)hh * NN + (size_t)(rok ? row : 0)) * 128 + kc;
        short8v ah = rok ? *(const short8v*)(h1hi + ao) : z8;
        short8v al = rok ? *(const short8v*)(h1lo + ao) : z8;
#pragma unroll
        for (int j = 0; j < 8; j++) {
            int c = j * 16 + m;
            size_t bo = (size_t)c * 384 + k0 + g * 8;
            short8v bh = *(const short8v*)(W2Th + bo);
            short8v bl = *(const short8v*)(W2Tl + bo);
            acc[j] = __builtin_amdgcn_mfma_f32_16x16x32_bf16(ah, bh, acc[j], 0, 0, 0);
            acc[j] = __builtin_amdgcn_mfma_f32_16x16x32_bf16(ah, bl, acc[j], 0, 0, 0);
            acc[j] = __builtin_amdgcn_mfma_f32_16x16x32_bf16(al, bh, acc[j], 0, 0, 0);
        }
    }
#pragma unroll
    for (int j = 0; j < 8; j++) {
        int c = j * 16 + m;
#pragma unroll
        for (int r = 0; r < 4; r++) {
            int orow = rb + w * 16 + g * 4 + r;
            if (orow < NN) h2[(size_t)orow * D2 + c] = acc[j][r];
        }
    }
}

// ===== alpha2: per-node dot(h2_row, a_src2/a_dst2) =====
__global__ __launch_bounds__(256) void k_alpha2(const float* __restrict__ h2,
                                                const float* __restrict__ aS,
                                                const float* __restrict__ aD,
                                                float* __restrict__ as2,
                                                float* __restrict__ ad2) {
    int n = blockIdx.x * 4 + (threadIdx.x >> 6);
    int l = threadIdx.x & 63;
    if (n >= NN) return;
    float v0 = h2[(size_t)n * D2 + l], v1 = h2[(size_t)n * D2 + 64 + l];
    float ps = v0 * aS[l] + v1 * aS[64 + l];
    float pd = v0 * aD[l] + v1 * aD[64 + l];
    for (int o = 32; o > 0; o >>= 1) {
        ps += __shfl_down(ps, o);
        pd += __shfl_down(pd, o);
    }
    if (l == 0) {
        as2[n] = ps;
        ad2[n] = pd;
    }
}

// ===== layer-2: fused softmax+aggregate+relu+POOL (atomicMax into poolbuf) =====
__global__ __launch_bounds__(128) void k_agg2f(const float* __restrict__ h2,
                                               const float* __restrict__ as2,
                                               const float* __restrict__ ad2,
                                               const int* __restrict__ off,
                                               const int* __restrict__ csr_src,
                                               const float* __restrict__ b2,
                                               unsigned* __restrict__ poolbuf) {
    int n = blockIdx.x, t = threadIdx.x;
    int e0 = off[n], e1 = off[n + 1];
    float adv = ad2[n];
    __shared__ int ssrc[64];
    __shared__ float sw[64];
    __shared__ float red[64];
    float acc = 0.f, ps = 0.f;
    for (int base = e0; base < e1; base += 64) {
        int c = min(64, e1 - base);
        __syncthreads();
        if (t < c) {
            int s = csr_src[base + t];
            ssrc[t] = s;
            float w = __expf(lrelu(as2[s] + adv));
            sw[t] = w;
            ps += w;
        }
        __syncthreads();
        for (int j = 0; j < c; j++) acc += h2[(size_t)ssrc[j] * D2 + t] * sw[j];
    }
    __syncthreads();
    if (t < 64) red[t] = ps;
    __syncthreads();
    for (int sr = 32; sr > 0; sr >>= 1) {
        if (t < sr) red[t] += red[t + sr];
        __syncthreads();
    }
    float v = fmaxf(acc / red[0] + b2[t], 0.f);
    int g = (int)(((long long)n * GG) / NN);   // batch[n] = n*G//N
    atomicMax(&poolbuf[g * D2 + t], fenc(v));
}

// ===== MLP head =====
__global__ __launch_bounds__(128) void k_mlp(const unsigned* __restrict__ poolbuf,
                                             const float* __restrict__ Wg,
                                             const float* __restrict__ bg,
                                             const float* __restrict__ Wf1,
                                             const float* __restrict__ bf1,
                                             const float* __restrict__ Wf2,
                                             const float* __restrict__ bf2,
                                             const float* __restrict__ Wo,
                                             const float* __restrict__ bo,
                                             float* __restrict__ out) {
    int g = blockIdx.x;
    int t = threadIdx.x;
    __shared__ float pool[D2];
    __shared__ float a1[64];
    __shared__ float a2[32];
    __shared__ float a3[16];
    pool[t] = fdec(poolbuf[g * D2 + t]);
    __syncthreads();
    if (t < 64) {
        float acc = bg[t];
        for (int k = 0; k < D2; k++) acc += pool[k] * Wg[k * 64 + t];
        a1[t] = fmaxf(acc, 0.f);
    }
    __syncthreads();
    if (t < 32) {
        float acc = bf1[t];
        for (int k = 0; k < 64; k++) acc += a1[k] * Wf1[k * 32 + t];
        a2[t] = fmaxf(acc, 0.f);
    }
    __syncthreads();
    if (t < 16) {
        float acc = bf2[t];
        for (int k = 0; k < 32; k++) acc += a2[k] * Wf2[k * 16 + t];
        a3[t] = fmaxf(acc, 0.f);
    }
    __syncthreads();
    if (t == 0) {
        float acc = bo[0];
        for (int k = 0; k < 16; k++) acc += a3[k] * Wo[k];
        out[g] = acc;
    }
}

extern "C" void kernel_launch(void* const* d_in, const int* in_sizes, int n_in,
                              void* d_out, int out_size, void* d_ws, size_t ws_size,
                              hipStream_t stream) {
    const float* x = (const float*)d_in[0];
    const int* ei = (const int*)d_in[1];
    const float* W1 = (const float*)d_in[3];
    const float* aS1 = (const float*)d_in[4];
    const float* aD1 = (const float*)d_in[5];
    const float* b1 = (const float*)d_in[6];
    const float* W2 = (const float*)d_in[7];
    const float* aS2 = (const float*)d_in[8];
    const float* aD2 = (const float*)d_in[9];
    const float* b2 = (const float*)d_in[10];
    const float* Wg = (const float*)d_in[11];
    const float* bg = (const float*)d_in[12];
    const float* Wf1 = (const float*)d_in[13];
    const float* bf1 = (const float*)d_in[14];
    const float* Wf2 = (const float*)d_in[15];
    const float* bf2 = (const float*)d_in[16];
    const float* Wo = (const float*)d_in[17];
    const float* bo = (const float*)d_in[18];
    float* out = (float*)d_out;

    const int* src = ei;
    const int* dst = ei + EE;

    char* ws = (char*)d_ws;
    size_t o = 0;
    auto alloc = [&](size_t bytes) -> char* {
        char* p = ws + o;
        o += (bytes + 255) & ~(size_t)255;
        return p;
    };
    float* was = (float*)alloc((size_t)FIN * H1 * 4);
    float* wad = (float*)alloc((size_t)FIN * H1 * 4);
    ushort_t* W1Th = (ushort_t*)alloc((size_t)H1 * 128 * 128 * 2);
    ushort_t* W1Tl = (ushort_t*)alloc((size_t)H1 * 128 * 128 * 2);
    ushort_t* W2Th = (ushort_t*)alloc((size_t)128 * 384 * 2);
    ushort_t* W2Tl = (ushort_t*)alloc((size_t)128 * 384 * 2);
    float* as1 = (float*)alloc((size_t)NN * H1 * 4);
    float* ad1 = (float*)alloc((size_t)NN * H1 * 4);
    int* cnt = (int*)alloc((size_t)NN * 4);
    int* off = (int*)alloc((size_t)(NN + 1) * 4);
    int* cur = (int*)alloc((size_t)NN * 4);
    int* csr_src = (int*)alloc((size_t)EE * 4);
    ushort_t* xgh = (ushort_t*)alloc((size_t)H1 * NN * 128 * 2);
    ushort_t* xgl = (ushort_t*)alloc((size_t)H1 * NN * 128 * 2);
    ushort_t* h1hi = (ushort_t*)alloc((size_t)H1 * NN * 128 * 2);
    ushort_t* h1lo = (ushort_t*)alloc((size_t)H1 * NN * 128 * 2);
    float* h2 = (float*)alloc((size_t)NN * D2 * 4);
    float* as2 = (float*)alloc((size_t)NN * 4);
    float* ad2 = (float*)alloc((size_t)NN * 4);
    unsigned* poolbuf = (unsigned*)alloc((size_t)GG * D2 * 4);
    (void)ws_size;

    hipMemsetAsync(cnt, 0, (size_t)NN * 4, stream);
    hipMemsetAsync(cur, 0, (size_t)NN * 4, stream);
    hipMemsetAsync(poolbuf, 0, (size_t)GG * D2 * 4, stream);

    const int EB = (EE + 255) / 256;

    k_wa<<<(2 * FIN * H1 + 255) / 256, 256, 0, stream>>>(W1, aS1, aD1, was, wad);
    k_prep1m<<<(H1 * 128 * 128 + 255) / 256, 256, 0, stream>>>(W1, W1Th, W1Tl);
    k_prep2m<<<(128 * 384 + 255) / 256, 256, 0, stream>>>(W2, W2Th, W2Tl);
    k_alpha1x<<<(NN + 3) / 4, 256, 0, stream>>>(x, was, wad, as1, ad1);
    k_count<<<EB, 256, 0, stream>>>(dst, cnt);
    k_scan<<<1, 1024, 0, stream>>>(cnt, off);
    k_scatter<<<EB, 256, 0, stream>>>(src, dst, off, cur, csr_src);
    k_aggx<<<NN, 128, 0, stream>>>(x, as1, ad1, off, csr_src, xgh, xgl);
    k_gemm1m<<<dim3((NN + 63) / 64, H1), 256, 0, stream>>>(xgh, xgl, W1Th, W1Tl, b1, h1hi, h1lo);
    k_gemm2m<<<(NN + 63) / 64, 256, 0, stream>>>(h1hi, h1lo, W2Th, W2Tl, h2);
    k_alpha2<<<(NN + 3) / 4, 256, 0, stream>>>(h2, aS2, aD2, as2, ad2);
    k_agg2f<<<NN, 128, 0, stream>>>(h2, as2, ad2, off, csr_src, b2, poolbuf);
    k_mlp<<<GG, 128, 0, stream>>>(poolbuf, Wg, bg, Wf1, bf1, Wf2, bf2, Wo, bo, out);
}

// Round 11
// 300.679 us; speedup vs baseline: 1.1361x; 1.0929x over previous
//
#include <hip/hip_runtime.h>

#define NN 20000
#define EE 660000      // 640000 + 20000 self loops
#define GG 64
#define FIN 114
#define H1 3
#define F1 342         // H1*FIN
#define D2 128
#define NEG 0.2f

typedef __attribute__((ext_vector_type(8))) short short8v;
typedef __attribute__((ext_vector_type(4))) float f32x4;
typedef unsigned short ushort_t;

__device__ inline unsigned fenc(float f) {
    unsigned u = __float_as_uint(f);
    return (u & 0x80000000u) ? ~u : (u | 0x80000000u);
}
__device__ inline float fdec(unsigned u) {
    return (u & 0x80000000u) ? __uint_as_float(u & 0x7FFFFFFFu) : __uint_as_float(~u);
}
__device__ inline float lrelu(float x) { return x > 0.f ? x : NEG * x; }

// fp32 -> bf16 hi (truncate) + bf16 lo (RNE of residual); x ≈ hi + lo to ~2^-17
__device__ inline void split2(float x, ushort_t& hi, ushort_t& lo) {
    unsigned u = __float_as_uint(x);
    unsigned uh = u & 0xFFFF0000u;
    hi = (ushort_t)(uh >> 16);
    float r = x - __uint_as_float(uh);
    unsigned v = __float_as_uint(r);
    unsigned vh = (v + 0x7FFFu + ((v >> 16) & 1u)) & 0xFFFF0000u;
    lo = (ushort_t)(vh >> 16);
}

// ===== fold a_src/a_dst through W1 =====
__global__ void k_wa(const float* __restrict__ W1, const float* __restrict__ aS,
                     const float* __restrict__ aD, float* __restrict__ was,
                     float* __restrict__ wad) {
    int tid = blockIdx.x * 256 + threadIdx.x;
    if (tid >= 2 * FIN * H1) return;
    int which = tid >= FIN * H1;
    int i = which ? tid - FIN * H1 : tid;
    int k = i / H1, h = i % H1;
    const float* a = which ? aD : aS;
    float s = 0.f;
    for (int d = 0; d < FIN; d++) s += W1[k * F1 + h * FIN + d] * a[h * FIN + d];
    (which ? wad : was)[i] = s;
}

// ===== W1 prep: W1T[h][c][k] hi/lo bf16, c,k in [0,128) zero-padded =====
__global__ void k_prep1m(const float* __restrict__ W1, ushort_t* __restrict__ W1Th,
                         ushort_t* __restrict__ W1Tl) {
    int tid = blockIdx.x * 256 + threadIdx.x;
    if (tid >= H1 * 128 * 128) return;
    int h = tid / (128 * 128);
    int rem = tid & (128 * 128 - 1);
    int c = rem >> 7, k = rem & 127;
    float v = (c < FIN && k < FIN) ? W1[k * F1 + h * FIN + c] : 0.f;
    ushort_t hi, lo;
    split2(v, hi, lo);
    W1Th[tid] = hi;
    W1Tl[tid] = lo;
}

// ===== W2 prep: W2T[c][hk] hi/lo bf16, hk = h*128+k (k zero-padded 114..127) =====
__global__ void k_prep2m(const float* __restrict__ W2, ushort_t* __restrict__ W2Th,
                         ushort_t* __restrict__ W2Tl) {
    int tid = blockIdx.x * 256 + threadIdx.x;
    if (tid >= 128 * 384) return;
    int c = tid / 384;
    int hk = tid - c * 384;
    int h = hk >> 7, k = hk & 127;
    float v = (k < FIN) ? W2[(h * FIN + k) * D2 + c] : 0.f;
    ushort_t hi, lo;
    split2(v, hi, lo);
    W2Th[tid] = hi;
    W2Tl[tid] = lo;
}

// ===== as1/ad1 = x @ was/wad =====
__global__ __launch_bounds__(256) void k_alpha1x(const float* __restrict__ x,
                                                 const float* __restrict__ was,
                                                 const float* __restrict__ wad,
                                                 float* __restrict__ as1,
                                                 float* __restrict__ ad1) {
    int n = blockIdx.x * 4 + (threadIdx.x >> 6);
    int l = threadIdx.x & 63;
    if (n >= NN) return;
    float x0 = x[n * FIN + l];
    float x1 = (l < FIN - 64) ? x[n * FIN + 64 + l] : 0.f;
    float s[H1], d[H1];
#pragma unroll
    for (int h = 0; h < H1; h++) {
        float w0s = was[l * H1 + h], w0d = wad[l * H1 + h];
        float w1s = (l < FIN - 64) ? was[(64 + l) * H1 + h] : 0.f;
        float w1d = (l < FIN - 64) ? wad[(64 + l) * H1 + h] : 0.f;
        s[h] = x0 * w0s + x1 * w1s;
        d[h] = x0 * w0d + x1 * w1d;
    }
#pragma unroll
    for (int o = 32; o > 0; o >>= 1) {
#pragma unroll
        for (int h = 0; h < H1; h++) {
            s[h] += __shfl_down(s[h], o);
            d[h] += __shfl_down(d[h], o);
        }
    }
    if (l == 0) {
#pragma unroll
        for (int h = 0; h < H1; h++) {
            as1[n * H1 + h] = s[h];
            ad1[n * H1 + h] = d[h];
        }
    }
}

// ===================== CSR build =====================
__global__ void k_count(const int* __restrict__ dst, int* __restrict__ cnt) {
    int e = blockIdx.x * 256 + threadIdx.x;
    if (e < EE) atomicAdd(&cnt[dst[e]], 1);
}

__global__ __launch_bounds__(1024) void k_scan(const int* __restrict__ cnt,
                                               int* __restrict__ off) {
    __shared__ int part[1024];
    int t = threadIdx.x;
    const int CH = 20;
    int loc[CH];
    int s = 0;
    int base = t * CH;
    for (int i = 0; i < CH; i++) {
        int idx = base + i;
        int v = (idx < NN) ? cnt[idx] : 0;
        loc[i] = s;
        s += v;
    }
    part[t] = s;
    __syncthreads();
    for (int d = 1; d < 1024; d <<= 1) {
        int v = (t >= d) ? part[t - d] : 0;
        __syncthreads();
        part[t] += v;
        __syncthreads();
    }
    int pre = (t == 0) ? 0 : part[t - 1];
    for (int i = 0; i < CH; i++) {
        int idx = base + i;
        if (idx < NN) off[idx] = pre + loc[i];
    }
    if (t == 1023) off[NN] = part[1023];
}

__global__ void k_scatter(const int* __restrict__ src, const int* __restrict__ dst,
                          const int* __restrict__ off, int* __restrict__ cur,
                          int* __restrict__ csr_src) {
    int e = blockIdx.x * 256 + threadIdx.x;
    if (e < EE) {
        int d = dst[e];
        int pos = off[d] + atomicAdd(&cur[d], 1);
        csr_src[pos] = src[e];
    }
}

// ===== layer-1: fused softmax+aggregate of x -> xg hi/lo bf16 [3][N][128] =====
__global__ __launch_bounds__(128) void k_aggx(const float* __restrict__ x,
                                              const float* __restrict__ as1,
                                              const float* __restrict__ ad1,
                                              const int* __restrict__ off,
                                              const int* __restrict__ csr_src,
                                              ushort_t* __restrict__ xgh,
                                              ushort_t* __restrict__ xgl) {
    int n = blockIdx.x, t = threadIdx.x;
    int e0 = off[n], e1 = off[n + 1];
    float adv0 = ad1[n * H1 + 0], adv1 = ad1[n * H1 + 1], adv2 = ad1[n * H1 + 2];
    __shared__ int ssrc[64];
    __shared__ float sw[64][H1];
    __shared__ float red[64][H1];
    float acc0 = 0.f, acc1 = 0.f, acc2 = 0.f;
    float ps0 = 0.f, ps1 = 0.f, ps2 = 0.f;
    for (int base = e0; base < e1; base += 64) {
        int c = min(64, e1 - base);
        __syncthreads();
        if (t < c) {
            int s = csr_src[base + t];
            ssrc[t] = s;
            float w0 = __expf(lrelu(as1[s * H1 + 0] + adv0));
            float w1 = __expf(lrelu(as1[s * H1 + 1] + adv1));
            float w2 = __expf(lrelu(as1[s * H1 + 2] + adv2));
            sw[t][0] = w0; sw[t][1] = w1; sw[t][2] = w2;
            ps0 += w0; ps1 += w1; ps2 += w2;
        }
        __syncthreads();
        if (t < FIN) {
            for (int j = 0; j < c; j++) {
                float xv = x[ssrc[j] * FIN + t];
                acc0 += xv * sw[j][0];
                acc1 += xv * sw[j][1];
                acc2 += xv * sw[j][2];
            }
        }
    }
    __syncthreads();
    if (t < 64) { red[t][0] = ps0; red[t][1] = ps1; red[t][2] = ps2; }
    __syncthreads();
    for (int sr = 32; sr > 0; sr >>= 1) {
        if (t < sr) {
            red[t][0] += red[t + sr][0];
            red[t][1] += red[t + sr][1];
            red[t][2] += red[t + sr][2];
        }
        __syncthreads();
    }
    float i0 = 1.f / red[0][0], i1 = 1.f / red[0][1], i2 = 1.f / red[0][2];
    float v0 = (t < FIN) ? acc0 * i0 : 0.f;
    float v1 = (t < FIN) ? acc1 * i1 : 0.f;
    float v2 = (t < FIN) ? acc2 * i2 : 0.f;
    ushort_t hi, lo;
    split2(v0, hi, lo);
    xgh[(size_t)0 * NN * 128 + n * 128 + t] = hi;
    xgl[(size_t)0 * NN * 128 + n * 128 + t] = lo;
    split2(v1, hi, lo);
    xgh[(size_t)1 * NN * 128 + n * 128 + t] = hi;
    xgl[(size_t)1 * NN * 128 + n * 128 + t] = lo;
    split2(v2, hi, lo);
    xgh[(size_t)2 * NN * 128 + n * 128 + t] = hi;
    xgl[(size_t)2 * NN * 128 + n * 128 + t] = lo;
}

// ===== GEMM1 (MFMA bf16x3, batched frag loads): h1 = ELU(xagg_h @ W1_h + b1) =====
// grid (157,3) x 256 thr; wave w owns rows rb+w*32..+31 (2 rowgroups), cols 0..127.
// Per k0: 16 B-frag loads + 4 A-frag loads (all batched) -> 1 wait -> 48 MFMAs.
__global__ __launch_bounds__(256) void k_gemm1m(const ushort_t* __restrict__ xgh,
                                                const ushort_t* __restrict__ xgl,
                                                const ushort_t* __restrict__ W1Th,
                                                const ushort_t* __restrict__ W1Tl,
                                                const float* __restrict__ b1,
                                                ushort_t* __restrict__ h1hi,
                                                ushort_t* __restrict__ h1lo) {
    int h = blockIdx.y;
    int rb = blockIdx.x * 128;
    int w = threadIdx.x >> 6, l = threadIdx.x & 63;
    int m = l & 15, g = l >> 4;
    int r0 = rb + w * 32 + m;
    int r1 = r0 + 16;
    bool ok0 = (r0 < NN), ok1 = (r1 < NN);
    const ushort_t* xh = xgh + (size_t)h * NN * 128;
    const ushort_t* xl = xgl + (size_t)h * NN * 128;
    const ushort_t* Bh = W1Th + (size_t)h * 128 * 128;
    const ushort_t* Bl = W1Tl + (size_t)h * 128 * 128;
    const short8v z8 = {0, 0, 0, 0, 0, 0, 0, 0};
    f32x4 acc0[8], acc1[8];
#pragma unroll
    for (int j = 0; j < 8; j++) {
        acc0[j] = (f32x4){0.f, 0.f, 0.f, 0.f};
        acc1[j] = (f32x4){0.f, 0.f, 0.f, 0.f};
    }
#pragma unroll
    for (int k0 = 0; k0 < 128; k0 += 32) {
        int ka = k0 + g * 8;
        short8v a0h = ok0 ? *(const short8v*)(xh + (size_t)r0 * 128 + ka) : z8;
        short8v a0l = ok0 ? *(const short8v*)(xl + (size_t)r0 * 128 + ka) : z8;
        short8v a1h = ok1 ? *(const short8v*)(xh + (size_t)r1 * 128 + ka) : z8;
        short8v a1l = ok1 ? *(const short8v*)(xl + (size_t)r1 * 128 + ka) : z8;
        short8v bh[8], bl[8];
#pragma unroll
        for (int j = 0; j < 8; j++) {
            size_t bo = (size_t)(j * 16 + m) * 128 + ka;
            bh[j] = *(const short8v*)(Bh + bo);
            bl[j] = *(const short8v*)(Bl + bo);
        }
#pragma unroll
        for (int j = 0; j < 8; j++) {
            acc0[j] = __builtin_amdgcn_mfma_f32_16x16x32_bf16(a0h, bh[j], acc0[j], 0, 0, 0);
            acc1[j] = __builtin_amdgcn_mfma_f32_16x16x32_bf16(a1h, bh[j], acc1[j], 0, 0, 0);
            acc0[j] = __builtin_amdgcn_mfma_f32_16x16x32_bf16(a0h, bl[j], acc0[j], 0, 0, 0);
            acc1[j] = __builtin_amdgcn_mfma_f32_16x16x32_bf16(a1h, bl[j], acc1[j], 0, 0, 0);
            acc0[j] = __builtin_amdgcn_mfma_f32_16x16x32_bf16(a0l, bh[j], acc0[j], 0, 0, 0);
            acc1[j] = __builtin_amdgcn_mfma_f32_16x16x32_bf16(a1l, bh[j], acc1[j], 0, 0, 0);
        }
    }
    // epilogue: bias + ELU + bf16 split; pad cols -> 0
    ushort_t* Hh = h1hi + (size_t)h * NN * 128;
    ushort_t* Hl = h1lo + (size_t)h * NN * 128;
#pragma unroll
    for (int j = 0; j < 8; j++) {
        int c = j * 16 + m;
        float bv = (c < FIN) ? b1[h * FIN + c] : 0.f;
#pragma unroll
        for (int r = 0; r < 4; r++) {
            int orow0 = rb + w * 32 + g * 4 + r;
            int orow1 = orow0 + 16;
            if (orow0 < NN) {
                float v = acc0[j][r] + bv;
                v = v > 0.f ? v : expm1f(v);
                ushort_t hi = 0, lo = 0;
                if (c < FIN) split2(v, hi, lo);
                Hh[(size_t)orow0 * 128 + c] = hi;
                Hl[(size_t)orow0 * 128 + c] = lo;
            }
            if (orow1 < NN) {
                float v = acc1[j][r] + bv;
                v = v > 0.f ? v : expm1f(v);
                ushort_t hi = 0, lo = 0;
                if (c < FIN) split2(v, hi, lo);
                Hh[(size_t)orow1 * 128 + c] = hi;
                Hl[(size_t)orow1 * 128 + c] = lo;
            }
        }
    }
}

// ===== GEMM2 (MFMA bf16x3, batched frag loads): h2 = h1 @ W2, K=384 =====
__global__ __launch_bounds__(256) void k_gemm2m(const ushort_t* __restrict__ h1hi,
                                                const ushort_t* __restrict__ h1lo,
                                                const ushort_t* __restrict__ W2Th,
                                                const ushort_t* __restrict__ W2Tl,
                                                float* __restrict__ h2) {
    int rb = blockIdx.x * 128;
    int w = threadIdx.x >> 6, l = threadIdx.x & 63;
    int m = l & 15, g = l >> 4;
    int r0 = rb + w * 32 + m;
    int r1 = r0 + 16;
    bool ok0 = (r0 < NN), ok1 = (r1 < NN);
    const short8v z8 = {0, 0, 0, 0, 0, 0, 0, 0};
    f32x4 acc0[8], acc1[8];
#pragma unroll
    for (int j = 0; j < 8; j++) {
        acc0[j] = (f32x4){0.f, 0.f, 0.f, 0.f};
        acc1[j] = (f32x4){0.f, 0.f, 0.f, 0.f};
    }
#pragma unroll
    for (int k0 = 0; k0 < 384; k0 += 32) {
        int hh = k0 >> 7;
        int kc = (k0 & 127) + g * 8;
        size_t a0o = ((size_t)hh * NN + (size_t)(ok0 ? r0 : 0)) * 128 + kc;
        size_t a1o = ((size_t)hh * NN + (size_t)(ok1 ? r1 : 0)) * 128 + kc;
        short8v a0h = ok0 ? *(const short8v*)(h1hi + a0o) : z8;
        short8v a0l = ok0 ? *(const short8v*)(h1lo + a0o) : z8;
        short8v a1h = ok1 ? *(const short8v*)(h1hi + a1o) : z8;
        short8v a1l = ok1 ? *(const short8v*)(h1lo + a1o) : z8;
        short8v bh[8], bl[8];
#pragma unroll
        for (int j = 0; j < 8; j++) {
            size_t bo = (size_t)(j * 16 + m) * 384 + k0 + g * 8;
            bh[j] = *(const short8v*)(W2Th + bo);
            bl[j] = *(const short8v*)(W2Tl + bo);
        }
#pragma unroll
        for (int j = 0; j < 8; j++) {
            acc0[j] = __builtin_amdgcn_mfma_f32_16x16x32_bf16(a0h, bh[j], acc0[j], 0, 0, 0);
            acc1[j] = __builtin_amdgcn_mfma_f32_16x16x32_bf16(a1h, bh[j], acc1[j], 0, 0, 0);
            acc0[j] = __builtin_amdgcn_mfma_f32_16x16x32_bf16(a0h, bl[j], acc0[j], 0, 0, 0);
            acc1[j] = __builtin_amdgcn_mfma_f32_16x16x32_bf16(a1h, bl[j], acc1[j], 0, 0, 0);
            acc0[j] = __builtin_amdgcn_mfma_f32_16x16x32_bf16(a0l, bh[j], acc0[j], 0, 0, 0);
            acc1[j] = __builtin_amdgcn_mfma_f32_16x16x32_bf16(a1l, bh[j], acc1[j], 0, 0, 0);
        }
    }
#pragma unroll
    for (int j = 0; j < 8; j++) {
        int c = j * 16 + m;
#pragma unroll
        for (int r = 0; r < 4; r++) {
            int orow0 = rb + w * 32 + g * 4 + r;
            int orow1 = orow0 + 16;
            if (orow0 < NN) h2[(size_t)orow0 * D2 + c] = acc0[j][r];
            if (orow1 < NN) h2[(size_t)orow1 * D2 + c] = acc1[j][r];
        }
    }
}

// ===== alpha2: per-node dot(h2_row, a_src2/a_dst2) =====
__global__ __launch_bounds__(256) void k_alpha2(const float* __restrict__ h2,
                                                const float* __restrict__ aS,
                                                const float* __restrict__ aD,
                                                float* __restrict__ as2,
                                                float* __restrict__ ad2) {
    int n = blockIdx.x * 4 + (threadIdx.x >> 6);
    int l = threadIdx.x & 63;
    if (n >= NN) return;
    float v0 = h2[(size_t)n * D2 + l], v1 = h2[(size_t)n * D2 + 64 + l];
    float ps = v0 * aS[l] + v1 * aS[64 + l];
    float pd = v0 * aD[l] + v1 * aD[64 + l];
    for (int o = 32; o > 0; o >>= 1) {
        ps += __shfl_down(ps, o);
        pd += __shfl_down(pd, o);
    }
    if (l == 0) {
        as2[n] = ps;
        ad2[n] = pd;
    }
}

// ===== layer-2: fused softmax+aggregate+relu+POOL (atomicMax into poolbuf) =====
__global__ __launch_bounds__(128) void k_agg2f(const float* __restrict__ h2,
                                               const float* __restrict__ as2,
                                               const float* __restrict__ ad2,
                                               const int* __restrict__ off,
                                               const int* __restrict__ csr_src,
                                               const float* __restrict__ b2,
                                               unsigned* __restrict__ poolbuf) {
    int n = blockIdx.x, t = threadIdx.x;
    int e0 = off[n], e1 = off[n + 1];
    float adv = ad2[n];
    __shared__ int ssrc[64];
    __shared__ float sw[64];
    __shared__ float red[64];
    float acc = 0.f, ps = 0.f;
    for (int base = e0; base < e1; base += 64) {
        int c = min(64, e1 - base);
        __syncthreads();
        if (t < c) {
            int s = csr_src[base + t];
            ssrc[t] = s;
            float w = __expf(lrelu(as2[s] + adv));
            sw[t] = w;
            ps += w;
        }
        __syncthreads();
        for (int j = 0; j < c; j++) acc += h2[(size_t)ssrc[j] * D2 + t] * sw[j];
    }
    __syncthreads();
    if (t < 64) red[t] = ps;
    __syncthreads();
    for (int sr = 32; sr > 0; sr >>= 1) {
        if (t < sr) red[t] += red[t + sr];
        __syncthreads();
    }
    float v = fmaxf(acc / red[0] + b2[t], 0.f);
    int g = (int)(((long long)n * GG) / NN);   // batch[n] = n*G//N
    atomicMax(&poolbuf[g * D2 + t], fenc(v));
}

// ===== MLP head =====
__global__ __launch_bounds__(128) void k_mlp(const unsigned* __restrict__ poolbuf,
                                             const float* __restrict__ Wg,
                                             const float* __restrict__ bg,
                                             const float* __restrict__ Wf1,
                                             const float* __restrict__ bf1,
                                             const float* __restrict__ Wf2,
                                             const float* __restrict__ bf2,
                                             const float* __restrict__ Wo,
                                             const float* __restrict__ bo,
                                             float* __restrict__ out) {
    int g = blockIdx.x;
    int t = threadIdx.x;
    __shared__ float pool[D2];
    __shared__ float a1[64];
    __shared__ float a2[32];
    __shared__ float a3[16];
    pool[t] = fdec(poolbuf[g * D2 + t]);
    __syncthreads();
    if (t < 64) {
        float acc = bg[t];
        for (int k = 0; k < D2; k++) acc += pool[k] * Wg[k * 64 + t];
        a1[t] = fmaxf(acc, 0.f);
    }
    __syncthreads();
    if (t < 32) {
        float acc = bf1[t];
        for (int k = 0; k < 64; k++) acc += a1[k] * Wf1[k * 32 + t];
        a2[t] = fmaxf(acc, 0.f);
    }
    __syncthreads();
    if (t < 16) {
        float acc = bf2[t];
        for (int k = 0; k < 32; k++) acc += a2[k] * Wf2[k * 16 + t];
        a3[t] = fmaxf(acc, 0.f);
    }
    __syncthreads();
    if (t == 0) {
        float acc = bo[0];
        for (int k = 0; k < 16; k++) acc += a3[k] * Wo[k];
        out[g] = acc;
    }
}

extern "C" void kernel_launch(void* const* d_in, const int* in_sizes, int n_in,
                              void* d_out, int out_size, void* d_ws, size_t ws_size,
                              hipStream_t stream) {
    const float* x = (const float*)d_in[0];
    const int* ei = (const int*)d_in[1];
    const float* W1 = (const float*)d_in[3];
    const float* aS1 = (const float*)d_in[4];
    const float* aD1 = (const float*)d_in[5];
    const float* b1 = (const float*)d_in[6];
    const float* W2 = (const float*)d_in[7];
    const float* aS2 = (const float*)d_in[8];
    const float* aD2 = (const float*)d_in[9];
    const float* b2 = (const float*)d_in[10];
    const float* Wg = (const float*)d_in[11];
    const float* bg = (const float*)d_in[12];
    const float* Wf1 = (const float*)d_in[13];
    const float* bf1 = (const float*)d_in[14];
    const float* Wf2 = (const float*)d_in[15];
    const float* bf2 = (const float*)d_in[16];
    const float* Wo = (const float*)d_in[17];
    const float* bo = (const float*)d_in[18];
    float* out = (float*)d_out;

    const int* src = ei;
    const int* dst = ei + EE;

    char* ws = (char*)d_ws;
    size_t o = 0;
    auto alloc = [&](size_t bytes) -> char* {
        char* p = ws + o;
        o += (bytes + 255) & ~(size_t)255;
        return p;
    };
    float* was = (float*)alloc((size_t)FIN * H1 * 4);
    float* wad = (float*)alloc((size_t)FIN * H1 * 4);
    ushort_t* W1Th = (ushort_t*)alloc((size_t)H1 * 128 * 128 * 2);
    ushort_t* W1Tl = (ushort_t*)alloc((size_t)H1 * 128 * 128 * 2);
    ushort_t* W2Th = (ushort_t*)alloc((size_t)128 * 384 * 2);
    ushort_t* W2Tl = (ushort_t*)alloc((size_t)128 * 384 * 2);
    float* as1 = (float*)alloc((size_t)NN * H1 * 4);
    float* ad1 = (float*)alloc((size_t)NN * H1 * 4);
    int* cnt = (int*)alloc((size_t)NN * 4);
    int* off = (int*)alloc((size_t)(NN + 1) * 4);
    int* cur = (int*)alloc((size_t)NN * 4);
    int* csr_src = (int*)alloc((size_t)EE * 4);
    ushort_t* xgh = (ushort_t*)alloc((size_t)H1 * NN * 128 * 2);
    ushort_t* xgl = (ushort_t*)alloc((size_t)H1 * NN * 128 * 2);
    ushort_t* h1hi = (ushort_t*)alloc((size_t)H1 * NN * 128 * 2);
    ushort_t* h1lo = (ushort_t*)alloc((size_t)H1 * NN * 128 * 2);
    float* h2 = (float*)alloc((size_t)NN * D2 * 4);
    float* as2 = (float*)alloc((size_t)NN * 4);
    float* ad2 = (float*)alloc((size_t)NN * 4);
    unsigned* poolbuf = (unsigned*)alloc((size_t)GG * D2 * 4);
    (void)ws_size;

    hipMemsetAsync(cnt, 0, (size_t)NN * 4, stream);
    hipMemsetAsync(cur, 0, (size_t)NN * 4, stream);
    hipMemsetAsync(poolbuf, 0, (size_t)GG * D2 * 4, stream);

    const int EB = (EE + 255) / 256;

    k_wa<<<(2 * FIN * H1 + 255) / 256, 256, 0, stream>>>(W1, aS1, aD1, was, wad);
    k_prep1m<<<(H1 * 128 * 128 + 255) / 256, 256, 0, stream>>>(W1, W1Th, W1Tl);
    k_prep2m<<<(128 * 384 + 255) / 256, 256, 0, stream>>>(W2, W2Th, W2Tl);
    k_alpha1x<<<(NN + 3) / 4, 256, 0, stream>>>(x, was, wad, as1, ad1);
    k_count<<<EB, 256, 0, stream>>>(dst, cnt);
    k_scan<<<1, 1024, 0, stream>>>(cnt, off);
    k_scatter<<<EB, 256, 0, stream>>>(src, dst, off, cur, csr_src);
    k_aggx<<<NN, 128, 0, stream>>>(x, as1, ad1, off, csr_src, xgh, xgl);
    k_gemm1m<<<dim3((NN + 127) / 128, H1), 256, 0, stream>>>(xgh, xgl, W1Th, W1Tl, b1, h1hi, h1lo);
    k_gemm2m<<<(NN + 127) / 128, 256, 0, stream>>>(h1hi, h1lo, W2Th, W2Tl, h2);
    k_alpha2<<<(NN + 3) / 4, 256, 0, stream>>>(h2, aS2, aD2, as2, ad2);
    k_agg2f<<<NN, 128, 0, stream>>>(h2, as2, ad2, off, csr_src, b2, poolbuf);
    k_mlp<<<GG, 128, 0, stream>>>(poolbuf, Wg, bg, Wf1, bf1, Wf2, bf2, Wo, bo, out);
}